// Round 4
// baseline (239.536 us; speedup 1.0000x reference)
//
#include <hip/hip_runtime.h>
#include <hip/hip_bf16.h>

typedef __attribute__((ext_vector_type(8))) short short8;
typedef __attribute__((ext_vector_type(4))) float f32x4;
typedef __attribute__((ext_vector_type(4))) int   i32x4;
typedef __attribute__((ext_vector_type(2))) unsigned int u32x2;

#define HH    32
#define CINN  32
#define COUTT 64
#define KNUM  15

static __device__ __forceinline__ short bfbits(float f) {
    __hip_bfloat16 h = __float2bfloat16(f);   // RNE, hw cvt (pairs to v_cvt_pk_bf16_f32)
    short s; __builtin_memcpy(&s, &h, 2); return s;
}
static __device__ __forceinline__ unsigned packbf(float a, float b) {
    return (unsigned)(unsigned short)bfbits(a) | ((unsigned)(unsigned short)bfbits(b) << 16);
}

// ---- pre-pass: feats f32 -> bf16 rows (one 64B cache line per row) ----
__global__ void cvt_feats_kernel(const float* __restrict__ f,
                                 unsigned short* __restrict__ o, int n8) {
    int i = blockIdx.x * blockDim.x + threadIdx.x;
    if (i < n8) {
        f32x4 v0 = *(const f32x4*)(f + i * 8);
        f32x4 v1 = *(const f32x4*)(f + i * 8 + 4);
        u32x2 s0 = { packbf(v0.x, v0.y), packbf(v0.z, v0.w) };
        u32x2 s1 = { packbf(v1.x, v1.y), packbf(v1.z, v1.w) };
        *(u32x2*)(o + i * 8)     = s0;
        *(u32x2*)(o + i * 8 + 4) = s1;
    }
}

__launch_bounds__(256, 6)
__global__ void kpconv_kernel(const float* __restrict__ query,
                              const float* __restrict__ support,
                              const int*   __restrict__ edge,
                              const unsigned short* __restrict__ featsbf,
                              const float* __restrict__ kpts,
                              const float* __restrict__ kvals,
                              float* __restrict__ out,
                              int nPts, int nBatch) {
    // LDS: af 15360 + xyz 8192 = 23552 B -> 6 blocks/CU (141KB)
    __shared__ unsigned short af_lds[KNUM * 64 * 8];
    __shared__ f32x4 xyz[4][4][32];     // [wave][point][h] — LINEAR (reads are broadcast)

    const int tid  = threadIdx.x;
    const int wave = tid >> 6;
    const int lane = tid & 63;
    const int g    = lane >> 4;
    const int low  = lane & 15;

    // ---- Kv -> registers, stage-2 B-frag order, even/odd channel permutation ----
    // k-index c' = g*8+i  ->  channel = 2*(c'&15) + (c'>>4)
    short8 kvreg[KNUM];
    #pragma unroll
    for (int s = 0; s < KNUM; ++s) {
        #pragma unroll
        for (int i = 0; i < 8; ++i) {
            int cp   = (g << 3) + i;
            int chan = (((cp & 15) << 1) | (cp >> 4));
            int o    = (wave << 4) + low;
            kvreg[s][i] = bfbits(kvals[(s * CINN + chan) * COUTT + o]);
        }
    }

    // lane's kernel point (stage-1 B-frag col = low); low==15 pad -> w=0 sentinel
    float px = 1e4f, py = 1e4f, pz = 1e4f;
    if (low < KNUM) { px = kpts[low * 3 + 0]; py = kpts[low * 3 + 1]; pz = kpts[low * 3 + 2]; }
    const float m2px = -2.f * px, m2py = -2.f * py, m2pz = -2.f * pz;
    const float pp2  = px * px + py * py + pz * pz;

    // phase-D per-lane address bases (add p*16 then XOR dM per point)
    const int  ld0  = (wave << 2) + ((g >> 1) << 4);
    const int  half = (g & 1) << 3;
    const int  dM   = (low & 7) << 4;
    const int  T0   = (low * 64 + ld0) * 16 + half;
    const int  T1   = T0 + 32 * 16;
    const bool sact = (low < KNUM);
    const unsigned lbase = (unsigned)lane << 4;

    __syncthreads();

    for (int b = blockIdx.x; b < nBatch; b += gridDim.x) {
        const int nbase = b * 16 + (wave << 2);

        // ===== phase A: neighbor offsets + |n|^2 for all 4 points (2 per pass) =====
        #pragma unroll
        for (int jj = 0; jj < 4; jj += 2) {
            int jpar = lane >> 5;
            int l32  = lane & 31;
            int n = nbase + jj + jpar;
            if (n >= nPts) n = nPts - 1;
            int e = edge[n * HH + l32];
            const float* qp = query + n * 3;
            const float* sp = support + (size_t)(unsigned)e * 3;
            float dx = sp[0] - qp[0];
            float dy = sp[1] - qp[1];
            float dz = sp[2] - qp[2];
            float nn = fmaf(dx, dx, fmaf(dy, dy, dz * dz));
            xyz[wave][jj + jpar][l32] = (f32x4){dx, dy, dz, nn};
        }

        // ===== stage 1: 4 points per wave =====
        #pragma unroll
        for (int p = 0; p < 4; ++p) {
            int n = nbase + p;
            if (n >= nPts) n = nPts - 1;

            // edge indices for this lane's quarter (broadcast 32B loads)
            const int* erow = edge + n * HH + (g << 3);
            i32x4 e0 = *(const i32x4*)erow;
            i32x4 e1 = *(const i32x4*)(erow + 4);

            // feature gathers: one dword = channels {2*low, 2*low+1} of row e
            unsigned fd[8];
            #pragma unroll
            for (int i = 0; i < 8; ++i) {
                unsigned e = (unsigned)((i < 4) ? e0[i & 3] : e1[i & 3]);
                unsigned off = (e << 6) + ((unsigned)low << 2);
                fd[i] = *(const unsigned*)((const char*)featsbf + off);
            }

            // weights w[kk=low][h=g*8+i]  (stage-1 B-frag, w^T); broadcast LDS reads
            short8 wf;
            const f32x4* xrow = &xyz[wave][p][g << 3];
            #pragma unroll
            for (int i = 0; i < 8; ++i) {
                f32x4 v = xrow[i];
                float d2 = fmaf(v.x, m2px, fmaf(v.y, m2py, fmaf(v.z, m2pz, v.w + pp2)));
                float w  = fmaxf(1.f - __builtin_amdgcn_sqrtf(d2), 0.f);
                wf[i] = bfbits(w);
            }

            // A-frags: a0 row=low -> channel 2*low, a1 -> channel 2*low+1
            short8 a0, a1;
            #pragma unroll
            for (int i = 0; i < 8; ++i) {
                a0[i] = (short)(fd[i] & 0xffffu);
                a1[i] = (short)(fd[i] >> 16);
            }

            f32x4 c0 = {0.f, 0.f, 0.f, 0.f}, c1 = {0.f, 0.f, 0.f, 0.f};
            c0 = __builtin_amdgcn_mfma_f32_16x16x32_bf16(a0, wf, c0, 0, 0, 0);
            c1 = __builtin_amdgcn_mfma_f32_16x16x32_bf16(a1, wf, c1, 0, 0, 0);

            // scatter weighted^T into stage-2 A-frag LDS (precomputed bases)
            if (sact) {
                u32x2 w0 = { packbf(c0.x, c0.y), packbf(c0.z, c0.w) };
                u32x2 w1 = { packbf(c1.x, c1.y), packbf(c1.z, c1.w) };
                *(u32x2*)((char*)af_lds + ((T0 + (p << 4)) ^ dM)) = w0;
                *(u32x2*)((char*)af_lds + ((T1 + (p << 4)) ^ dM)) = w1;
            }
        }
        __syncthreads();

        // ===== stage 2: out[p][o] = sum_s,c' weighted[p][c'] * Kv[s][pi(c')][o] =====
        f32x4 acc = {0.f, 0.f, 0.f, 0.f};
        #pragma unroll
        for (int s = 0; s < KNUM; ++s) {
            const char* ap = (const char*)af_lds + (lbase ^ (unsigned)((s & 7) << 4)) + s * 1024;
            short8 av = *(const short8*)ap;
            acc = __builtin_amdgcn_mfma_f32_16x16x32_bf16(av, kvreg[s], acc, 0, 0, 0);
        }

        {
            int n0 = b * 16 + (g << 2);
            float* orow = out + (size_t)(unsigned)n0 * COUTT + (wave << 4) + low;
            #pragma unroll
            for (int r = 0; r < 4; ++r) {
                if (n0 + r < nPts) orow[r * COUTT] = acc[r];
            }
        }
        __syncthreads();   // protect af_lds before next batch's stage-1
    }
}

extern "C" void kernel_launch(void* const* d_in, const int* in_sizes, int n_in,
                              void* d_out, int out_size, void* d_ws, size_t ws_size,
                              hipStream_t stream) {
    const float* query   = (const float*)d_in[0];
    const float* support = (const float*)d_in[1];
    const int*   edge    = (const int*)d_in[2];
    const float* feats   = (const float*)d_in[3];
    const float* kpts    = (const float*)d_in[4];
    const float* kvals   = (const float*)d_in[5];
    float* out = (float*)d_out;

    int nPts   = in_sizes[0] / 3;
    int nBatch = (nPts + 15) / 16;

    // pre-pass: bf16 feature rows (64B per row)
    unsigned short* featsbf = (unsigned short*)d_ws;
    int n8 = nPts * CINN / 8;
    hipLaunchKernelGGL(cvt_feats_kernel, dim3((n8 + 255) / 256), dim3(256), 0, stream,
                       feats, featsbf, n8);

    int grid = 1536;                 // persistent: 6 blocks/CU x 256 CU
    if (grid > nBatch) grid = nBatch;

    hipLaunchKernelGGL(kpconv_kernel, dim3(grid), dim3(256), 0, stream,
                       query, support, edge, featsbf, kpts, kvals, out, nPts, nBatch);
}

// Round 5
// 161.940 us; speedup vs baseline: 1.4792x; 1.4792x over previous
//
#include <hip/hip_runtime.h>
#include <hip/hip_bf16.h>

typedef __attribute__((ext_vector_type(8))) short short8;
typedef __attribute__((ext_vector_type(4))) float f32x4;
typedef __attribute__((ext_vector_type(2))) unsigned int u32x2;

#define HH    32
#define CINN  32
#define COUTT 64
#define KNUM  15

static __device__ __forceinline__ short bfbits(float f) {
    __hip_bfloat16 h = __float2bfloat16(f);   // RNE, hw cvt (pairs to v_cvt_pk_bf16_f32)
    short s; __builtin_memcpy(&s, &h, 2); return s;
}
static __device__ __forceinline__ unsigned packbf(float a, float b) {
    return (unsigned)(unsigned short)bfbits(a) | ((unsigned)(unsigned short)bfbits(b) << 16);
}

// ---- pre-pass: feats f32 -> bf16 rows (one 64B cache line per row) ----
__global__ void cvt_feats_kernel(const float* __restrict__ f,
                                 unsigned short* __restrict__ o, int n8) {
    int i = blockIdx.x * blockDim.x + threadIdx.x;
    if (i < n8) {
        f32x4 v0 = *(const f32x4*)(f + i * 8);
        f32x4 v1 = *(const f32x4*)(f + i * 8 + 4);
        u32x2 s0 = { packbf(v0.x, v0.y), packbf(v0.z, v0.w) };
        u32x2 s1 = { packbf(v1.x, v1.y), packbf(v1.z, v1.w) };
        *(u32x2*)(o + i * 8)     = s0;
        *(u32x2*)(o + i * 8 + 4) = s1;
    }
}

__launch_bounds__(256, 4)
__global__ void kpconv_kernel(const float* __restrict__ query,
                              const float* __restrict__ support,
                              const int*   __restrict__ edge,
                              const unsigned short* __restrict__ featsbf,
                              const float* __restrict__ kpts,
                              const float* __restrict__ kvals,
                              float* __restrict__ out,
                              int nPts, int nBatch) {
    // LDS: af 15360 + xyz 8192 = 23552 B -> 6 blocks/CU (141KB), 24 waves/CU
    __shared__ unsigned short af_lds[KNUM * 64 * 8];
    __shared__ f32x4 xyz[4][4][32];   // [wave][point][slot], slot = ((h&7)<<2)|(h>>3)

    const int tid  = threadIdx.x;
    const int wave = tid >> 6;
    const int lane = tid & 63;
    const int g    = lane >> 4;
    const int low  = lane & 15;
    const int jpar = lane >> 5;       // phase-A point parity
    const int l32  = lane & 31;       // phase-A neighbor id
    const int slotA = ((l32 & 7) << 2) | (l32 >> 3);   // bank-spread write slot

    // ---- Kv: stage-2 B-frag order, even/odd channel permutation ----
    // (compiler rematerializes these from L2 per batch; Kv is L2-resident)
    short8 kvreg[KNUM];
    #pragma unroll
    for (int s = 0; s < KNUM; ++s) {
        #pragma unroll
        for (int i = 0; i < 8; ++i) {
            int cp   = (g << 3) + i;
            int chan = (((cp & 15) << 1) | (cp >> 4));
            int o    = (wave << 4) + low;
            kvreg[s][i] = bfbits(kvals[(s * CINN + chan) * COUTT + o]);
        }
    }

    // lane's kernel point (stage-1 B-frag col = low); low==15 pad -> w=0 sentinel
    float px = 1e4f, py = 1e4f, pz = 1e4f;
    if (low < KNUM) { px = kpts[low * 3 + 0]; py = kpts[low * 3 + 1]; pz = kpts[low * 3 + 2]; }

    // phase-D per-lane address bases (add p*16 then XOR dM per point)
    const int  ld0  = (wave << 2) + ((g >> 1) << 4);
    const int  half = (g & 1) << 3;
    const int  dM   = (low & 7) << 4;
    const int  T0   = (low * 64 + ld0) * 16 + half;
    const int  T1   = T0 + 32 * 16;
    const bool sact = (low < KNUM);
    const unsigned lbase = (unsigned)lane << 4;

    // ---- phase-A prefetch registers (T14 split: issue early / ds_write late) ----
    int   eN[2]; float sxN[2], syN[2], szN[2], qxN[2], qyN[2], qzN[2];
    #define LOADA(bb)                                                          \
        _Pragma("unroll")                                                      \
        for (int k = 0; k < 2; ++k) {                                          \
            int n = (bb) * 16 + (wave << 2) + (k << 1) + jpar;                 \
            if (n >= nPts) n = nPts - 1;                                       \
            int e = edge[n * HH + l32];                                        \
            eN[k] = e;                                                         \
            const float* qp = query + n * 3;                                   \
            const float* sp = support + (size_t)(unsigned)e * 3;               \
            sxN[k] = sp[0]; syN[k] = sp[1]; szN[k] = sp[2];                    \
            qxN[k] = qp[0]; qyN[k] = qp[1]; qzN[k] = qp[2];                    \
        }

    LOADA(blockIdx.x);

    for (int b = blockIdx.x; b < nBatch; b += gridDim.x) {
        // ---- commit prefetched phase A into xyz (wave-private, no barrier) ----
        #pragma unroll
        for (int k = 0; k < 2; ++k) {
            f32x4 v = { sxN[k] - qxN[k], syN[k] - qyN[k], szN[k] - qzN[k],
                        __int_as_float(eN[k]) };
            xyz[wave][(k << 1) + jpar][slotA] = v;
        }

        // ---- issue next batch's gathers NOW (overlap with stage-1 + barrier) ----
        LOADA(b + gridDim.x);

        // ===== stage 1: 4 points per wave =====
        #pragma unroll
        for (int p = 0; p < 4; ++p) {
            // quarter g reads h=g*8+i at slot (i<<2)|g -> disjoint bank groups
            const f32x4* xrow = &xyz[wave][p][g];

            unsigned fd[8];
            short8 wf;
            #pragma unroll
            for (int i = 0; i < 8; ++i) {
                f32x4 v = xrow[i << 2];
                unsigned e = (unsigned)__float_as_int(v.w);
                fd[i] = *(const unsigned*)((const char*)featsbf + (e << 6) + ((unsigned)low << 2));
                float tx = v.x - px, ty = v.y - py, tz = v.z - pz;
                float d2 = fmaf(tx, tx, fmaf(ty, ty, tz * tz));
                wf[i] = bfbits(fmaxf(1.f - __builtin_amdgcn_sqrtf(d2), 0.f));
            }

            // A-frags: a0 row=low -> channel 2*low, a1 -> channel 2*low+1
            short8 a0, a1;
            #pragma unroll
            for (int i = 0; i < 8; ++i) {
                a0[i] = (short)(fd[i] & 0xffffu);
                a1[i] = (short)(fd[i] >> 16);
            }

            f32x4 c0 = {0.f, 0.f, 0.f, 0.f}, c1 = {0.f, 0.f, 0.f, 0.f};
            c0 = __builtin_amdgcn_mfma_f32_16x16x32_bf16(a0, wf, c0, 0, 0, 0);
            c1 = __builtin_amdgcn_mfma_f32_16x16x32_bf16(a1, wf, c1, 0, 0, 0);

            // scatter weighted^T into stage-2 A-frag LDS (precomputed bases)
            if (sact) {
                u32x2 w0 = { packbf(c0.x, c0.y), packbf(c0.z, c0.w) };
                u32x2 w1 = { packbf(c1.x, c1.y), packbf(c1.z, c1.w) };
                *(u32x2*)((char*)af_lds + ((T0 + (p << 4)) ^ dM)) = w0;
                *(u32x2*)((char*)af_lds + ((T1 + (p << 4)) ^ dM)) = w1;
            }
        }
        __syncthreads();

        // ===== stage 2: out[p][o] = sum_s,c' weighted[p][c'] * Kv[s][pi(c')][o] =====
        f32x4 acc = {0.f, 0.f, 0.f, 0.f};
        #pragma unroll
        for (int s = 0; s < KNUM; ++s) {
            const char* ap = (const char*)af_lds + (lbase ^ (unsigned)((s & 7) << 4)) + s * 1024;
            short8 av = *(const short8*)ap;
            acc = __builtin_amdgcn_mfma_f32_16x16x32_bf16(av, kvreg[s], acc, 0, 0, 0);
        }

        {
            int n0 = b * 16 + (g << 2);
            float* orow = out + (size_t)(unsigned)n0 * COUTT + (wave << 4) + low;
            #pragma unroll
            for (int r = 0; r < 4; ++r) {
                if (n0 + r < nPts) orow[r * COUTT] = acc[r];
            }
        }
        __syncthreads();   // protect af_lds before next batch's stage-1
    }
    #undef LOADA
}

extern "C" void kernel_launch(void* const* d_in, const int* in_sizes, int n_in,
                              void* d_out, int out_size, void* d_ws, size_t ws_size,
                              hipStream_t stream) {
    const float* query   = (const float*)d_in[0];
    const float* support = (const float*)d_in[1];
    const int*   edge    = (const int*)d_in[2];
    const float* feats   = (const float*)d_in[3];
    const float* kpts    = (const float*)d_in[4];
    const float* kvals   = (const float*)d_in[5];
    float* out = (float*)d_out;

    int nPts   = in_sizes[0] / 3;
    int nBatch = (nPts + 15) / 16;

    // pre-pass: bf16 feature rows (64B per row)
    unsigned short* featsbf = (unsigned short*)d_ws;
    int n8 = nPts * CINN / 8;
    hipLaunchKernelGGL(cvt_feats_kernel, dim3((n8 + 255) / 256), dim3(256), 0, stream,
                       feats, featsbf, n8);

    int grid = 1536;                 // 6 blocks/CU via LDS limit (residency not capped by LB)
    if (grid > nBatch) grid = nBatch;

    hipLaunchKernelGGL(kpconv_kernel, dim3(grid), dim3(256), 0, stream,
                       query, support, edge, featsbf, kpts, kvals, out, nPts, nBatch);
}

// Round 6
// 161.640 us; speedup vs baseline: 1.4819x; 1.0019x over previous
//
#include <hip/hip_runtime.h>
#include <hip/hip_bf16.h>

typedef __attribute__((ext_vector_type(8))) short short8;
typedef __attribute__((ext_vector_type(4))) float f32x4;
typedef __attribute__((ext_vector_type(2))) unsigned int u32x2;

#define HH    32
#define CINN  32
#define COUTT 64
#define KNUM  15

static __device__ __forceinline__ short bfbits(float f) {
    __hip_bfloat16 h = __float2bfloat16(f);   // RNE, hw cvt (pairs to v_cvt_pk_bf16_f32)
    short s; __builtin_memcpy(&s, &h, 2); return s;
}
static __device__ __forceinline__ unsigned packbf(float a, float b) {
    return (unsigned)(unsigned short)bfbits(a) | ((unsigned)(unsigned short)bfbits(b) << 16);
}

// LDS-only barrier: orders ds ops across waves WITHOUT draining global loads
// (raw s_barrier has no implicit vmcnt(0), unlike __syncthreads -- verified idiom)
static __device__ __forceinline__ void lds_barrier() {
    asm volatile("s_waitcnt lgkmcnt(0)" ::: "memory");
    __builtin_amdgcn_s_barrier();
    __builtin_amdgcn_sched_barrier(0);
}

// ---- pre-pass: feats f32 -> bf16 rows (one 64B cache line per row) ----
__global__ void cvt_feats_kernel(const float* __restrict__ f,
                                 unsigned short* __restrict__ o, int n8) {
    int i = blockIdx.x * blockDim.x + threadIdx.x;
    if (i < n8) {
        f32x4 v0 = *(const f32x4*)(f + i * 8);
        f32x4 v1 = *(const f32x4*)(f + i * 8 + 4);
        u32x2 s0 = { packbf(v0.x, v0.y), packbf(v0.z, v0.w) };
        u32x2 s1 = { packbf(v1.x, v1.y), packbf(v1.z, v1.w) };
        *(u32x2*)(o + i * 8)     = s0;
        *(u32x2*)(o + i * 8 + 4) = s1;
    }
}

__launch_bounds__(256, 4)
__global__ void kpconv_kernel(const float* __restrict__ query,
                              const float* __restrict__ support,
                              const int*   __restrict__ edge,
                              const unsigned short* __restrict__ featsbf,
                              const float* __restrict__ kpts,
                              const float* __restrict__ kvals,
                              float* __restrict__ out,
                              int nPts, int nBatch) {
    // LDS: af 15360 + xyz 8192 = 23552 B -> 6 blocks/CU (141KB)
    __shared__ unsigned short af_lds[KNUM * 64 * 8];
    __shared__ f32x4 xyz[4][4][32];   // [wave][point][slot], slot = ((h&7)<<2)|(h>>3)

    const int tid  = threadIdx.x;
    const int wave = tid >> 6;
    const int lane = tid & 63;
    const int g    = lane >> 4;
    const int low  = lane & 15;
    const int jpar = lane >> 5;       // phase-A point parity
    const int l32  = lane & 31;       // phase-A neighbor id
    const int slotA = ((l32 & 7) << 2) | (l32 >> 3);   // write slot (matches read (i<<2)|g)

    // ---- Kv: stage-2 B-frag order, even/odd channel permutation ----
    // (compiler remats these from L2 per batch; loads now float across barriers)
    short8 kvreg[KNUM];
    #pragma unroll
    for (int s = 0; s < KNUM; ++s) {
        #pragma unroll
        for (int i = 0; i < 8; ++i) {
            int cp   = (g << 3) + i;
            int chan = (((cp & 15) << 1) | (cp >> 4));
            int o    = (wave << 4) + low;
            kvreg[s][i] = bfbits(kvals[(s * CINN + chan) * COUTT + o]);
        }
    }

    // lane's kernel point (stage-1 B-frag col = low); low==15 pad -> w=0 sentinel
    float px = 1e4f, py = 1e4f, pz = 1e4f;
    if (low < KNUM) { px = kpts[low * 3 + 0]; py = kpts[low * 3 + 1]; pz = kpts[low * 3 + 2]; }

    // phase-D per-lane address bases (add p*16 then XOR dM per point)
    const int  ld0  = (wave << 2) + ((g >> 1) << 4);
    const int  half = (g & 1) << 3;
    const int  dM   = (low & 7) << 4;
    const int  T0   = (low * 64 + ld0) * 16 + half;
    const int  T1   = T0 + 32 * 16;
    const bool sact = (low < KNUM);
    const unsigned lbase = (unsigned)lane << 4;

    // ---- phase-A prefetch registers (issue early / commit late) ----
    int   eN[2]; float sxN[2], syN[2], szN[2], qxN[2], qyN[2], qzN[2];
    #define LOADA(bb)                                                          \
        _Pragma("unroll")                                                      \
        for (int k = 0; k < 2; ++k) {                                          \
            int n = (bb) * 16 + (wave << 2) + (k << 1) + jpar;                 \
            if (n >= nPts) n = nPts - 1;                                       \
            int e = edge[n * HH + l32];                                        \
            eN[k] = e;                                                         \
            const float* qp = query + n * 3;                                   \
            const float* sp = support + (size_t)(unsigned)e * 3;               \
            sxN[k] = sp[0]; syN[k] = sp[1]; szN[k] = sp[2];                    \
            qxN[k] = qp[0]; qyN[k] = qp[1]; qzN[k] = qp[2];                    \
        }

    LOADA(blockIdx.x);

    __syncthreads();   // one full barrier before the pipeline starts (init only)

    for (int b = blockIdx.x; b < nBatch; b += gridDim.x) {
        // ---- commit prefetched phase A into xyz (wave-private, no barrier) ----
        #pragma unroll
        for (int k = 0; k < 2; ++k) {
            f32x4 v = { sxN[k] - qxN[k], syN[k] - qyN[k], szN[k] - qzN[k],
                        __int_as_float(eN[k]) };
            xyz[wave][(k << 1) + jpar][slotA] = v;
        }

        // ---- issue next batch's gathers NOW (stay in flight across barriers) ----
        LOADA(b + gridDim.x);

        // ===== stage 1: 4 points per wave =====
        #pragma unroll
        for (int p = 0; p < 4; ++p) {
            // quarter g reads h=g*8+i at slot (i<<2)|g -> disjoint bank groups
            const f32x4* xrow = &xyz[wave][p][g];

            unsigned fd[8];
            short8 wf;
            #pragma unroll
            for (int i = 0; i < 8; ++i) {
                f32x4 v = xrow[i << 2];
                unsigned e = (unsigned)__float_as_int(v.w);
                fd[i] = *(const unsigned*)((const char*)featsbf + (e << 6) + ((unsigned)low << 2));
                float tx = v.x - px, ty = v.y - py, tz = v.z - pz;
                float d2 = fmaf(tx, tx, fmaf(ty, ty, tz * tz));
                wf[i] = bfbits(fmaxf(1.f - __builtin_amdgcn_sqrtf(d2), 0.f));
            }

            // A-frags: a0 row=low -> channel 2*low, a1 -> channel 2*low+1
            short8 a0, a1;
            #pragma unroll
            for (int i = 0; i < 8; ++i) {
                a0[i] = (short)(fd[i] & 0xffffu);
                a1[i] = (short)(fd[i] >> 16);
            }

            f32x4 c0 = {0.f, 0.f, 0.f, 0.f}, c1 = {0.f, 0.f, 0.f, 0.f};
            c0 = __builtin_amdgcn_mfma_f32_16x16x32_bf16(a0, wf, c0, 0, 0, 0);
            c1 = __builtin_amdgcn_mfma_f32_16x16x32_bf16(a1, wf, c1, 0, 0, 0);

            // scatter weighted^T into stage-2 A-frag LDS (precomputed bases)
            if (sact) {
                u32x2 w0 = { packbf(c0.x, c0.y), packbf(c0.z, c0.w) };
                u32x2 w1 = { packbf(c1.x, c1.y), packbf(c1.z, c1.w) };
                *(u32x2*)((char*)af_lds + ((T0 + (p << 4)) ^ dM)) = w0;
                *(u32x2*)((char*)af_lds + ((T1 + (p << 4)) ^ dM)) = w1;
            }
        }
        lds_barrier();   // af visible to all waves; global prefetches stay in flight

        // ===== stage 2: out[p][o] = sum_s,c' weighted[p][c'] * Kv[s][pi(c')][o] =====
        f32x4 acc = {0.f, 0.f, 0.f, 0.f};
        #pragma unroll
        for (int s = 0; s < KNUM; ++s) {
            const char* ap = (const char*)af_lds + (lbase ^ (unsigned)((s & 7) << 4)) + s * 1024;
            short8 av = *(const short8*)ap;
            acc = __builtin_amdgcn_mfma_f32_16x16x32_bf16(av, kvreg[s], acc, 0, 0, 0);
        }

        {
            int n0 = b * 16 + (g << 2);
            float* orow = out + (size_t)(unsigned)n0 * COUTT + (wave << 4) + low;
            #pragma unroll
            for (int r = 0; r < 4; ++r) {
                if (n0 + r < nPts) orow[r * COUTT] = acc[r];
            }
        }
        lds_barrier();   // af reads done before next batch's stage-1 overwrites
    }
    #undef LOADA
}

extern "C" void kernel_launch(void* const* d_in, const int* in_sizes, int n_in,
                              void* d_out, int out_size, void* d_ws, size_t ws_size,
                              hipStream_t stream) {
    const float* query   = (const float*)d_in[0];
    const float* support = (const float*)d_in[1];
    const int*   edge    = (const int*)d_in[2];
    const float* feats   = (const float*)d_in[3];
    const float* kpts    = (const float*)d_in[4];
    const float* kvals   = (const float*)d_in[5];
    float* out = (float*)d_out;

    int nPts   = in_sizes[0] / 3;
    int nBatch = (nPts + 15) / 16;

    // pre-pass: bf16 feature rows (64B per row)
    unsigned short* featsbf = (unsigned short*)d_ws;
    int n8 = nPts * CINN / 8;
    hipLaunchKernelGGL(cvt_feats_kernel, dim3((n8 + 255) / 256), dim3(256), 0, stream,
                       feats, featsbf, n8);

    int grid = 1536;                 // 6 blocks/CU via LDS limit
    if (grid > nBatch) grid = nBatch;

    hipLaunchKernelGGL(kpconv_kernel, dim3(grid), dim3(256), 0, stream,
                       query, support, edge, featsbf, kpts, kvals, out, nPts, nBatch);
}

// Round 7
// 139.119 us; speedup vs baseline: 1.7218x; 1.1619x over previous
//
#include <hip/hip_runtime.h>
#include <hip/hip_bf16.h>

typedef __attribute__((ext_vector_type(8))) short short8;
typedef __attribute__((ext_vector_type(4))) float f32x4;
typedef __attribute__((ext_vector_type(2))) unsigned int u32x2;

#define HH    32
#define CINN  32
#define COUTT 64
#define KNUM  15

static __device__ __forceinline__ short bfbits(float f) {
    __hip_bfloat16 h = __float2bfloat16(f);   // RNE, hw cvt
    short s; __builtin_memcpy(&s, &h, 2); return s;
}
static __device__ __forceinline__ unsigned packbf(float a, float b) {
    return (unsigned)(unsigned short)bfbits(a) | ((unsigned)(unsigned short)bfbits(b) << 16);
}

// LDS-only barrier: orders ds ops across waves WITHOUT draining global loads
static __device__ __forceinline__ void lds_barrier() {
    asm volatile("s_waitcnt lgkmcnt(0)" ::: "memory");
    __builtin_amdgcn_s_barrier();
    __builtin_amdgcn_sched_barrier(0);
}

// ---- pre-pass: feats f32 -> bf16 rows (one 64B cache line per row) ----
__global__ void cvt_feats_kernel(const float* __restrict__ f,
                                 unsigned short* __restrict__ o, int n8) {
    int i = blockIdx.x * blockDim.x + threadIdx.x;
    if (i < n8) {
        f32x4 v0 = *(const f32x4*)(f + i * 8);
        f32x4 v1 = *(const f32x4*)(f + i * 8 + 4);
        u32x2 s0 = { packbf(v0.x, v0.y), packbf(v0.z, v0.w) };
        u32x2 s1 = { packbf(v1.x, v1.y), packbf(v1.z, v1.w) };
        *(u32x2*)(o + i * 8)     = s0;
        *(u32x2*)(o + i * 8 + 4) = s1;
    }
}

__launch_bounds__(256, 3)
__global__ void kpconv_kernel(const float* __restrict__ query,
                              const float* __restrict__ support,
                              const int*   __restrict__ edge,
                              const unsigned short* __restrict__ featsbf,
                              const float* __restrict__ kpts,
                              const float* __restrict__ kvals,
                              float* __restrict__ out,
                              int nPts, int nBatch) {
    // LDS: af 15360 + xyz 8192 + earr 2048 = 25600 B
    __shared__ unsigned short af_lds[KNUM * 64 * 8];
    __shared__ f32x4 xyz[4][4][32];   // [wave][point][slot]: (dx,dy,dz,|n|^2)
    __shared__ int   earr[4][4][32];  // [wave][point][slot]: neighbor row id

    const int tid  = threadIdx.x;
    const int wave = tid >> 6;
    const int lane = tid & 63;
    const int g    = lane >> 4;
    const int low  = lane & 15;
    const int jpar = lane >> 5;       // phase-A point parity
    const int l32  = lane & 31;       // phase-A neighbor id
    const int slotA = ((l32 & 7) << 2) | (l32 >> 3);   // write slot; read = (i<<2)|g

    // ---- Kv once into VGPRs, PINNED (asm makes remat impossible) ----
    // kvu[s][d] packs frag elems {2d,2d+1}: chan = 2*(cp&15)+(cp>>4), cp=g*8+i
    unsigned kvu[KNUM][4];
    #pragma unroll
    for (int s = 0; s < KNUM; ++s) {
        #pragma unroll
        for (int d = 0; d < 4; ++d) {
            int cp0 = (g << 3) + 2 * d, cp1 = cp0 + 1;
            int ch0 = ((cp0 & 15) << 1) | (cp0 >> 4);
            int ch1 = ((cp1 & 15) << 1) | (cp1 >> 4);
            int o   = (wave << 4) + low;
            kvu[s][d] = packbf(kvals[(s * CINN + ch0) * COUTT + o],
                               kvals[(s * CINN + ch1) * COUTT + o]);
        }
        asm volatile("" : "+v"(kvu[s][0]), "+v"(kvu[s][1]),
                          "+v"(kvu[s][2]), "+v"(kvu[s][3]));
    }

    // lane's kernel point (stage-1 B-frag col = low); low==15 pad -> w=0 sentinel
    float px = 1e4f, py = 1e4f, pz = 1e4f;
    if (low < KNUM) { px = kpts[low * 3 + 0]; py = kpts[low * 3 + 1]; pz = kpts[low * 3 + 2]; }
    const float m2px = -2.f * px, m2py = -2.f * py, m2pz = -2.f * pz;
    const float ppsq = px * px + py * py + pz * pz;

    // phase-D per-lane address bases (add p*16 then XOR dM per point)
    const int  ld0  = (wave << 2) + ((g >> 1) << 4);
    const int  half = (g & 1) << 3;
    const int  dM   = (low & 7) << 4;
    const int  T0   = (low * 64 + ld0) * 16 + half;
    const int  T1   = T0 + 32 * 16;
    const bool sact = (low < KNUM);
    const unsigned lbase = (unsigned)lane << 4;

    // ---- phase-A prefetch registers (issue early / commit late) ----
    int   eN[2]; float sxN[2], syN[2], szN[2], qxN[2], qyN[2], qzN[2];
    #define LOADA(bb)                                                          \
        _Pragma("unroll")                                                      \
        for (int k = 0; k < 2; ++k) {                                          \
            int n = (bb) * 16 + (wave << 2) + (k << 1) + jpar;                 \
            if (n >= nPts) n = nPts - 1;                                       \
            int e = edge[n * HH + l32];                                        \
            eN[k] = e;                                                         \
            const float* qp = query + n * 3;                                   \
            const float* sp = support + (size_t)(unsigned)e * 3;               \
            sxN[k] = sp[0]; syN[k] = sp[1]; szN[k] = sp[2];                    \
            qxN[k] = qp[0]; qyN[k] = qp[1]; qzN[k] = qp[2];                    \
        }

    LOADA(blockIdx.x);

    __syncthreads();   // init barrier only

    for (int b = blockIdx.x; b < nBatch; b += gridDim.x) {
        // ---- commit prefetched phase A (wave-private, no barrier) ----
        #pragma unroll
        for (int k = 0; k < 2; ++k) {
            float dx = sxN[k] - qxN[k], dy = syN[k] - qyN[k], dz = szN[k] - qzN[k];
            float nn = fmaf(dx, dx, fmaf(dy, dy, dz * dz));
            xyz[wave][(k << 1) + jpar][slotA]  = (f32x4){dx, dy, dz, nn};
            earr[wave][(k << 1) + jpar][slotA] = eN[k];
        }

        // ---- issue next batch's gathers NOW ----
        LOADA(b + gridDim.x);

        // ===== stage 1: 4 points per wave, processed in pairs =====
        #pragma unroll
        for (int pb = 0; pb < 4; pb += 2) {
            // hoisted feature gathers for both points of the pair (16 in flight)
            unsigned fd[2][8];
            #pragma unroll
            for (int q = 0; q < 2; ++q) {
                #pragma unroll
                for (int i = 0; i < 8; ++i) {
                    unsigned e = (unsigned)earr[wave][pb + q][(i << 2) | g];
                    fd[q][i] = *(const unsigned*)((const char*)featsbf +
                                 (e << 6) + ((unsigned)low << 2));
                }
            }

            #pragma unroll
            for (int q = 0; q < 2; ++q) {
                const int p = pb + q;
                const f32x4* xrow = &xyz[wave][p][g];

                short8 wf, a0, a1;
                #pragma unroll
                for (int i = 0; i < 8; ++i) {
                    f32x4 v = xrow[i << 2];
                    float d2 = fmaf(v.x, m2px, fmaf(v.y, m2py,
                               fmaf(v.z, m2pz, v.w + ppsq)));
                    wf[i] = bfbits(fmaxf(1.f - __builtin_amdgcn_sqrtf(d2), 0.f));
                    a0[i] = (short)(fd[q][i] & 0xffffu);
                    a1[i] = (short)(fd[q][i] >> 16);
                }

                f32x4 c0 = {0.f, 0.f, 0.f, 0.f}, c1 = {0.f, 0.f, 0.f, 0.f};
                c0 = __builtin_amdgcn_mfma_f32_16x16x32_bf16(a0, wf, c0, 0, 0, 0);
                c1 = __builtin_amdgcn_mfma_f32_16x16x32_bf16(a1, wf, c1, 0, 0, 0);

                if (sact) {
                    u32x2 w0 = { packbf(c0.x, c0.y), packbf(c0.z, c0.w) };
                    u32x2 w1 = { packbf(c1.x, c1.y), packbf(c1.z, c1.w) };
                    *(u32x2*)((char*)af_lds + ((T0 + (p << 4)) ^ dM)) = w0;
                    *(u32x2*)((char*)af_lds + ((T1 + (p << 4)) ^ dM)) = w1;
                }
            }
        }
        lds_barrier();   // af visible; global prefetches stay in flight

        // ===== stage 2: out[p][o] = sum_s,c' weighted[p][c'] * Kv[s][pi(c')][o] =====
        f32x4 acc = {0.f, 0.f, 0.f, 0.f};
        #pragma unroll
        for (int s = 0; s < KNUM; ++s) {
            const char* ap = (const char*)af_lds + (lbase ^ (unsigned)((s & 7) << 4)) + s * 1024;
            short8 av = *(const short8*)ap;
            short8 bv; __builtin_memcpy(&bv, kvu[s], 16);
            acc = __builtin_amdgcn_mfma_f32_16x16x32_bf16(av, bv, acc, 0, 0, 0);
        }

        {
            int n0 = b * 16 + (g << 2);
            float* orow = out + (size_t)(unsigned)n0 * COUTT + (wave << 4) + low;
            #pragma unroll
            for (int r = 0; r < 4; ++r) {
                if (n0 + r < nPts) orow[r * COUTT] = acc[r];
            }
        }
        lds_barrier();   // af reads done before next batch overwrites
    }
    #undef LOADA
}

extern "C" void kernel_launch(void* const* d_in, const int* in_sizes, int n_in,
                              void* d_out, int out_size, void* d_ws, size_t ws_size,
                              hipStream_t stream) {
    const float* query   = (const float*)d_in[0];
    const float* support = (const float*)d_in[1];
    const int*   edge    = (const int*)d_in[2];
    const float* feats   = (const float*)d_in[3];
    const float* kpts    = (const float*)d_in[4];
    const float* kvals   = (const float*)d_in[5];
    float* out = (float*)d_out;

    int nPts   = in_sizes[0] / 3;
    int nBatch = (nPts + 15) / 16;

    // pre-pass: bf16 feature rows (64B per row)
    unsigned short* featsbf = (unsigned short*)d_ws;
    int n8 = nPts * CINN / 8;
    hipLaunchKernelGGL(cvt_feats_kernel, dim3((n8 + 255) / 256), dim3(256), 0, stream,
                       feats, featsbf, n8);

    int grid = 768;                  // 3 blocks/CU (VGPR-limited by design)
    if (grid > nBatch) grid = nBatch;

    hipLaunchKernelGGL(kpconv_kernel, dim3(grid), dim3(256), 0, stream,
                       query, support, edge, featsbf, kpts, kvals, out, nPts, nBatch);
}